// Round 1
// baseline (19550.015 us; speedup 1.0000x reference)
//
#include <hip/hip_runtime.h>
#include <cstdint>
#include <cstddef>

// PointerDecoder: B=64, L=T=512, E=128, H=256.
// Design: batch chains are independent -> one block per batch runs all 512
// steps (no grid sync). Prologue hoists ctx = context@Wc+bc and
// embProj = embed@Wih (x_new is always a row of embed_input, so x@Wih is a
// lookup). Alphas staged (B,T,L) in ws, transposed to (B,L,T) at the end.

#define DEV static __device__ __forceinline__

DEV float rl(float v, int l) {
    return __int_as_float(__builtin_amdgcn_readlane(__float_as_int(v), l));
}
DEV float fast_rcp(float d) {
    float r = __builtin_amdgcn_rcpf(d);
    return r * (2.0f - d * r);   // one Newton step -> ~1 ulp
}
DEV float fast_tanh(float x) {
    float e = __expf(fminf(2.0f * x, 88.0f));   // clamp avoids inf*0 NaN in NR
    return 1.0f - 2.0f * fast_rcp(1.0f + e);
}
DEV float fast_sigmoid(float x) {
    float e = __expf(fminf(-x, 88.0f));
    return fast_rcp(1.0f + e);
}

// ---------------- prologue: ctx = context @ Wc + bc  (rows of 256 -> 256) ---
__global__ __launch_bounds__(256) void k_ctx(const float* __restrict__ cin,
                                             const float* __restrict__ Wc,
                                             const float* __restrict__ bc,
                                             float* __restrict__ cout_) {
    __shared__ float rows[8][256];
    const int tid = threadIdx.x, lane = tid & 63;
    const long bl0 = (long)blockIdx.x * 8;
    for (int i = tid; i < 8 * 256; i += 256)
        rows[i >> 8][i & 255] = cin[bl0 * 256 + i];
    __syncthreads();
    float rr[8][4];
#pragma unroll
    for (int r = 0; r < 8; ++r)
#pragma unroll
        for (int q = 0; q < 4; ++q) rr[r][q] = rows[r][q * 64 + lane];
    float acc[8] = {0, 0, 0, 0, 0, 0, 0, 0};
#pragma unroll
    for (int kq = 0; kq < 4; ++kq) {
        for (int kk = 0; kk < 64; ++kk) {
            float wc = Wc[(kq * 64 + kk) * 256 + tid];
#pragma unroll
            for (int r = 0; r < 8; ++r) acc[r] += rl(rr[r][kq], kk) * wc;
        }
    }
    float bcv = bc[tid];
#pragma unroll
    for (int r = 0; r < 8; ++r) cout_[(bl0 + r) * 256 + tid] = acc[r] + bcv;
}

// ------------- prologue: y = x @ Wih  (rows of 128 -> 1024), used for embed
// and decoder_input. 8 rows per block, 256 threads * 4 cols.
__global__ __launch_bounds__(256) void k_proj(const float* __restrict__ xin,
                                              const float* __restrict__ Wih,
                                              float* __restrict__ yout) {
    __shared__ float rows[8][128];
    const int tid = threadIdx.x, lane = tid & 63;
    const long bl0 = (long)blockIdx.x * 8;
    for (int i = tid; i < 8 * 128; i += 256)
        rows[i >> 7][i & 127] = xin[bl0 * 128 + i];
    __syncthreads();
    float rr[8][2];
#pragma unroll
    for (int r = 0; r < 8; ++r)
#pragma unroll
        for (int q = 0; q < 2; ++q) rr[r][q] = rows[r][q * 64 + lane];
    float4 acc[8];
#pragma unroll
    for (int r = 0; r < 8; ++r) acc[r] = make_float4(0.f, 0.f, 0.f, 0.f);
#pragma unroll
    for (int eq = 0; eq < 2; ++eq) {
        for (int ee = 0; ee < 64; ++ee) {
            const float4 w4 =
                *(const float4*)(Wih + (size_t)(eq * 64 + ee) * 1024 + tid * 4);
#pragma unroll
            for (int r = 0; r < 8; ++r) {
                float xe = rl(rr[r][eq], ee);
                acc[r].x += xe * w4.x; acc[r].y += xe * w4.y;
                acc[r].z += xe * w4.z; acc[r].w += xe * w4.w;
            }
        }
    }
#pragma unroll
    for (int r = 0; r < 8; ++r)
        *(float4*)(yout + (bl0 + r) * 1024 + tid * 4) = acc[r];
}

// ------------- epilogue: out0[b,l,t] = alpha_ws[b,t,l] ------------------
__global__ __launch_bounds__(256) void k_tr(const float* __restrict__ aws,
                                            float* __restrict__ out0) {
    __shared__ float tile[32][33];
    const int b = blockIdx.z, l0 = blockIdx.x * 32, t0 = blockIdx.y * 32;
    const int tx = threadIdx.x, ty = threadIdx.y;
    const float* src = aws + ((size_t)b << 18);
    float* dst = out0 + ((size_t)b << 18);
#pragma unroll
    for (int i = 0; i < 32; i += 8)
        tile[ty + i][tx] = src[(size_t)(t0 + ty + i) * 512 + l0 + tx];
    __syncthreads();
#pragma unroll
    for (int i = 0; i < 32; i += 8)
        dst[(size_t)(l0 + ty + i) * 512 + t0 + tx] = tile[tx][ty + i];
}

// ---------------- main persistent kernel: one block per batch ---------------
__global__ __launch_bounds__(1024) void k_main(
    const float* __restrict__ h0, const float* __restrict__ c0,
    const float* __restrict__ Whh, const float* __restrict__ Wih,
    const float* __restrict__ Wq, const float* __restrict__ Wo,
    const float* __restrict__ bih, const float* __restrict__ bhh,
    const float* __restrict__ bq, const float* __restrict__ bo,
    const float* __restrict__ V, const float* __restrict__ embed,
    const float* __restrict__ dec_in, const float* __restrict__ ctx_ws,
    const float* __restrict__ emb_ws, const float* __restrict__ dec_ws,
    float* __restrict__ alpha_ws, float* __restrict__ out0,
    float* __restrict__ out1, float* __restrict__ out2,
    float* __restrict__ out3, int use_emb, int use_stage) {
    const int b = blockIdx.x;
    const int tid = threadIdx.x;
    const int lane = tid & 63;
    const int w = tid >> 6;     // wave id, 16 waves
    const int tt = tid & 255;
    const int p = tid >> 8;     // 4 k-parts (wave-uniform: p = w>>2)

    __shared__ __align__(16) float h_s[256];
    __shared__ __align__(16) float c_s[256];
    __shared__ __align__(16) float q_s[256];
    __shared__ __align__(16) float ah_s[256];
    __shared__ __align__(16) float gates_s[1024];
    __shared__ __align__(16) float bsum_s[1024];
    __shared__ __align__(16) float att_s[512];
    __shared__ __align__(16) float alpha_s[512];
    __shared__ __align__(16) float mask_s[512];
    __shared__ __align__(16) float bq_s[256];
    __shared__ __align__(16) float bo_s[256];
    __shared__ __align__(16) float x_s[128];
    __shared__ __align__(16) float red_s[4096];
    __shared__ float m_sh, s_sh;
    __shared__ int idx_sh;

    bsum_s[tid] = bih[tid] + bhh[tid];
    if (tid < 256) {
        h_s[tid] = h0[(b << 8) + tid];
        c_s[tid] = c0[(b << 8) + tid];
        bq_s[tid] = bq[tid];
        bo_s[tid] = bo[tid];
    }
    if (tid < 512) mask_s[tid] = 1.0f;
    if (!use_emb && tid < 128) x_s[tid] = dec_in[(b << 7) + tid];
    const float4 V4 = *(const float4*)(V + (lane << 2));
    __syncthreads();

    int cur = 0;
    for (int t = 0; t < 512; ++t) {
        // ---- P1: gates = x@Wih + h@Whh + biases ----
        {
            float hv = h_s[(p << 6) + lane];
            float4 acc = make_float4(0.f, 0.f, 0.f, 0.f);
            const float* wp = Whh + (size_t)(p << 6) * 1024 + (tt << 2);
#pragma unroll 8
            for (int kk = 0; kk < 64; ++kk) {
                float hk = rl(hv, kk);
                const float4 w4 = *(const float4*)(wp + (size_t)kk * 1024);
                acc.x += hk * w4.x; acc.y += hk * w4.y;
                acc.z += hk * w4.z; acc.w += hk * w4.w;
            }
            if (!use_emb) {
                float xv = x_s[(p << 5) + (lane & 31)];
                const float* wip = Wih + (size_t)(p << 5) * 1024 + (tt << 2);
#pragma unroll 8
                for (int ee = 0; ee < 32; ++ee) {
                    float xe = rl(xv, ee);
                    const float4 w4 = *(const float4*)(wip + (size_t)ee * 1024);
                    acc.x += xe * w4.x; acc.y += xe * w4.y;
                    acc.z += xe * w4.z; acc.w += xe * w4.w;
                }
            }
            *(float4*)(red_s + (p << 10) + (tt << 2)) = acc;
        }
        __syncthreads();
        {
            float g = red_s[tid] + red_s[1024 + tid] + red_s[2048 + tid] +
                      red_s[3072 + tid] + bsum_s[tid];
            if (use_emb) {
                const float* er = (t == 0)
                                      ? (dec_ws + ((size_t)b << 10))
                                      : (emb_ws + ((size_t)((b << 9) + cur) << 10));
                g += er[tid];
            }
            gates_s[tid] = g;
        }
        __syncthreads();
        // ---- P2: LSTM cell update ----
        if (tid < 256) {
            float ig = fast_sigmoid(gates_s[tid]);
            float fg = fast_sigmoid(gates_s[256 + tid]);
            float gg = fast_tanh(gates_s[512 + tid]);
            float og = fast_sigmoid(gates_s[768 + tid]);
            float cn = fg * c_s[tid] + ig * gg;
            c_s[tid] = cn;
            h_s[tid] = og * fast_tanh(cn);   // h_s now holds h_t
        }
        __syncthreads();
        // ---- P3: q = h_t @ Wq + bq ----
        {
            float hv = h_s[(p << 6) + lane];
            float a = 0.f;
            const float* wp = Wq + (size_t)(p << 6) * 256 + tt;
#pragma unroll 8
            for (int kk = 0; kk < 64; ++kk) a += rl(hv, kk) * wp[(size_t)kk * 256];
            red_s[(p << 8) + tt] = a;
        }
        __syncthreads();
        if (tid < 256)
            q_s[tid] = red_s[tid] + red_s[256 + tid] + red_s[512 + tid] +
                       red_s[768 + tid] + bq_s[tid];
        __syncthreads();
        // ---- P4: att[l] = sum_h V[h]*tanh(q[h]+ctx[l,h]); masked -> -1e9 ----
        {
            const float4 q4 = *(const float4*)(q_s + (lane << 2));
            const float* cbase = ctx_ws + (((size_t)b << 9) << 8);
            for (int l = w; l < 512; l += 16) {          // one wave per l
                if (mask_s[l] == 0.f) {
                    if (lane == 0) att_s[l] = -1e9f;
                } else {
                    const float4 cc =
                        *(const float4*)(cbase + ((size_t)l << 8) + (lane << 2));
                    float s = V4.x * fast_tanh(q4.x + cc.x) +
                              V4.y * fast_tanh(q4.y + cc.y) +
                              V4.z * fast_tanh(q4.z + cc.z) +
                              V4.w * fast_tanh(q4.w + cc.w);
#pragma unroll
                    for (int off = 32; off > 0; off >>= 1)
                        s += __shfl_xor(s, off, 64);
                    if (lane == 0) att_s[l] = s;
                }
            }
        }
        __syncthreads();
        // ---- P5: argmax (first-occurrence, like np) + softmax ----
        if (tid < 512) {
            float v = att_s[tid];
            int bi = tid;
#pragma unroll
            for (int off = 1; off < 64; off <<= 1) {
                float ov = __shfl_xor(v, off, 64);
                int oi = __shfl_xor(bi, off, 64);
                if (ov > v || (ov == v && oi < bi)) { v = ov; bi = oi; }
            }
            if (lane == 0) { red_s[w] = v; ((int*)red_s)[64 + w] = bi; }
        }
        __syncthreads();
        if (tid == 0) {
            float bv = red_s[0];
            int bb = ((int*)red_s)[64];
            for (int i = 1; i < 8; ++i) {
                float v2 = red_s[i];
                int i2 = ((int*)red_s)[64 + i];
                if (v2 > bv || (v2 == bv && i2 < bb)) { bv = v2; bb = i2; }
            }
            m_sh = bv;
            idx_sh = bb;
        }
        __syncthreads();
        {
            float mmax = m_sh;
            if (tid < 512) {
                float e = __expf(att_s[tid] - mmax);   // masked -> exactly 0
                alpha_s[tid] = e;
                float ss = e;
#pragma unroll
                for (int off = 32; off > 0; off >>= 1)
                    ss += __shfl_xor(ss, off, 64);
                if (lane == 0) red_s[128 + w] = ss;
            }
        }
        __syncthreads();
        if (tid == 0) {
            float S = 0.f;
            for (int i = 0; i < 8; ++i) S += red_s[128 + i];
            s_sh = S;
        }
        __syncthreads();
        {
            float Sv = s_sh;
            if (tid < 512) {
                float a = alpha_s[tid] / Sv;    // IEEE div, matches ref
                alpha_s[tid] = a;
                if (use_stage)
                    alpha_ws[((((size_t)b << 9) + t) << 9) + tid] = a;
                else
                    out0[((size_t)b << 18) + ((size_t)tid << 9) + t] = a;
            }
            cur = idx_sh;
            if (tid == 0) {
                out1[(b << 9) + t] = (float)cur;
                mask_s[cur] = 0.f;              // mask for NEXT step
            }
            if (!use_emb && tid < 128)
                x_s[tid] = embed[((size_t)((b << 9) + cur) << 7) + tid];
        }
        __syncthreads();
        // ---- P6: attn_h = sum_l alpha[l]*ctx[l,:]  (skip alpha==0) ----
        {
            float ax = 0.f, ay = 0.f, az = 0.f, aw = 0.f;
            const float* cbase = ctx_ws + (((size_t)b << 9) << 8) + (lane << 2);
            for (int l = w; l < 512; l += 16) {
                float al = alpha_s[l];
                if (al != 0.f) {
                    const float4 cc = *(const float4*)(cbase + ((size_t)l << 8));
                    ax += al * cc.x; ay += al * cc.y;
                    az += al * cc.z; aw += al * cc.w;
                }
            }
            float4 a4 = make_float4(ax, ay, az, aw);
            *(float4*)(red_s + (w << 8) + (lane << 2)) = a4;
        }
        __syncthreads();
        if (tid < 256) {
            float s = 0.f;
#pragma unroll
            for (int i = 0; i < 16; ++i) s += red_s[(i << 8) + tid];
            ah_s[tid] = s;
        }
        __syncthreads();
        // ---- P7: h_new = tanh([attn_h, h_t] @ Wo + bo) ----
        {
            float av0 = (p < 2) ? ah_s[(p << 7) + lane]
                                : h_s[((p - 2) << 7) + lane];
            float av1 = (p < 2) ? ah_s[(p << 7) + 64 + lane]
                                : h_s[((p - 2) << 7) + 64 + lane];
            float a = 0.f;
            const float* wp = Wo + (size_t)(p << 7) * 256 + tt;
#pragma unroll 8
            for (int kk = 0; kk < 64; ++kk) a += rl(av0, kk) * wp[(size_t)kk * 256];
#pragma unroll 8
            for (int kk = 0; kk < 64; ++kk)
                a += rl(av1, kk) * wp[(size_t)(64 + kk) * 256];
            red_s[(p << 8) + tt] = a;
        }
        __syncthreads();
        if (tid < 256)
            h_s[tid] = fast_tanh(red_s[tid] + red_s[256 + tid] +
                                 red_s[512 + tid] + red_s[768 + tid] + bo_s[tid]);
        __syncthreads();
    }
    if (tid < 256) {
        out2[(b << 8) + tid] = h_s[tid];   // h_f
        out3[(b << 8) + tid] = c_s[tid];   // c_f
    }
}

extern "C" void kernel_launch(void* const* d_in, const int* in_sizes, int n_in,
                              void* d_out, int out_size, void* d_ws,
                              size_t ws_size, hipStream_t stream) {
    const float* embed = (const float*)d_in[0];    // (64,512,128)
    const float* dec   = (const float*)d_in[1];    // (64,128)
    const float* h0    = (const float*)d_in[2];    // (64,256)
    const float* c0    = (const float*)d_in[3];    // (64,256)
    const float* ctxin = (const float*)d_in[4];    // (64,512,256)
    const float* Wih   = (const float*)d_in[5];    // (128,1024)
    const float* bih   = (const float*)d_in[6];
    const float* Whh   = (const float*)d_in[7];    // (256,1024)
    const float* bhh   = (const float*)d_in[8];
    const float* Wo    = (const float*)d_in[9];    // (512,256)
    const float* bo    = (const float*)d_in[10];
    const float* Wq    = (const float*)d_in[11];   // (256,256)
    const float* bq    = (const float*)d_in[12];
    const float* Wc    = (const float*)d_in[13];   // (256,256)
    const float* bc    = (const float*)d_in[14];
    const float* V     = (const float*)d_in[15];   // (256,)

    float* out0 = (float*)d_out;            // (64,512,512) alphas
    float* out1 = out0 + 16777216;          // (64,512) pointers (as float)
    float* out2 = out1 + 32768;             // (64,256) h_f
    float* out3 = out2 + 16384;             // (64,256) c_f

    float* ws = (float*)d_ws;
    const size_t wsf = ws_size / 4;
    const size_t SZ_CTX = 8388608, SZ_DEC = 65536, SZ_EMB = 33554432,
                 SZ_AL = 16777216;
    const int use_emb = wsf >= SZ_CTX + SZ_DEC + SZ_EMB;
    const size_t al_off = use_emb ? (SZ_CTX + SZ_DEC + SZ_EMB) : SZ_CTX;
    const int use_stage = wsf >= al_off + SZ_AL;

    float* ws_ctx = ws;
    float* ws_dec = ws + SZ_CTX;
    float* ws_emb = ws + SZ_CTX + SZ_DEC;
    float* ws_al  = ws + al_off;

    k_ctx<<<dim3(4096), dim3(256), 0, stream>>>(ctxin, Wc, bc, ws_ctx);
    if (use_emb) {
        k_proj<<<dim3(4096), dim3(256), 0, stream>>>(embed, Wih, ws_emb);
        k_proj<<<dim3(8), dim3(256), 0, stream>>>(dec, Wih, ws_dec);
    }
    k_main<<<dim3(64), dim3(1024), 0, stream>>>(
        h0, c0, Whh, Wih, Wq, Wo, bih, bhh, bq, bo, V, embed, dec, ws_ctx,
        ws_emb, ws_dec, ws_al, out0, out1, out2, out3, use_emb, use_stage);
    if (use_stage)
        k_tr<<<dim3(16, 16, 64), dim3(32, 8), 0, stream>>>(ws_al, out0);
}